// Round 3
// baseline (182.420 us; speedup 1.0000x reference)
//
#include <hip/hip_runtime.h>

// Lucas-Kanade sparse optical flow, 21x21 windows, Scharr gradients,
// Gaussian weights. B=16, H=W=1008, HS=WS=48, T=2304, P=441.
// Output: (B, T, 2, 2) float32 = [win_pos, vels].

constexpr int HH   = 1008;
constexpr int WW   = 1008;
constexpr int WINN = 21;
constexpr int HSN  = 48;
constexpr int WSN  = 48;
constexpr int TN   = HSN * WSN;        // 2304
constexpr int SEGS = 4;                // quarter-strips per window-row
constexpr int COLS = WW / SEGS;        // 252 active columns per block
constexpr int WPB  = WSN / SEGS;       // 12 windows per block

__global__ __launch_bounds__(256)
void SparseOptFlowLK_kernel(const float* __restrict__ imgs,
                            float* __restrict__ out) {
    const int bi  = blockIdx.x;                 // 0 .. B*48*4-1
    const int b   = bi / (HSN * SEGS);
    const int rem = bi % (HSN * SEGS);
    const int hy  = rem / SEGS;                 // window-row 0..47
    const int seg = rem % SEGS;                 // quarter 0..3

    const float* __restrict__ ff = imgs + (size_t)b * (2ull * HH * WW);
    const float* __restrict__ sf = ff + (size_t)HH * WW;

    __shared__ float colsum[5][COLS];           // per-column partial sums
    __shared__ float red[WPB][5];               // per-window sums

    const int lx = threadIdx.x;

    if (lx < COLS) {
        const int gx = seg * COLS + lx;         // global column
        const bool hl = (gx > 0);
        const bool hr = (gx < WW - 1);

        // separable Gaussian weights: exp(-(d-10)^2 / 8)
        float wtab[WINN];
        #pragma unroll
        for (int y = 0; y < WINN; ++y) {
            const float dy = (float)(y - 10);
            wtab[y] = expf(-dy * dy * 0.125f);
        }
        const int   xw  = lx % WINN;            // 252 = 12*21, so lx%21 == gx%21
        const float wxw = wtab[xw];

        const int g0 = hy * WINN;               // first interior row (global)

        // rolling 3-row x 3-col register window
        float rm0, rm1, rm2, rc0, rc1, rc2;
        if (g0 > 0) {
            const float* r = ff + (size_t)(g0 - 1) * WW;
            rm1 = r[gx];
            rm0 = hl ? r[gx - 1] : 0.0f;
            rm2 = hr ? r[gx + 1] : 0.0f;
        } else {
            rm0 = rm1 = rm2 = 0.0f;             // SAME zero pad (top image edge)
        }
        {
            const float* r = ff + (size_t)g0 * WW;
            rc1 = r[gx];
            rc0 = hl ? r[gx - 1] : 0.0f;
            rc2 = hr ? r[gx + 1] : 0.0f;
        }

        float sA = 0.0f, sB = 0.0f, sD = 0.0f, sX = 0.0f, sY = 0.0f;

        #pragma unroll
        for (int y = 0; y < WINN; ++y) {
            float rp0, rp1, rp2;
            const int gp = g0 + y + 1;
            if (gp < HH) {
                const float* r = ff + (size_t)gp * WW;
                rp1 = r[gx];
                rp0 = hl ? r[gx - 1] : 0.0f;
                rp2 = hr ? r[gx + 1] : 0.0f;
            } else {
                rp0 = rp1 = rp2 = 0.0f;         // SAME zero pad (bottom image edge)
            }

            // Scharr (cross-correlation, matches XLA conv semantics)
            const float Ix = 3.0f * (rm2 - rm0) + 10.0f * (rc2 - rc0) + 3.0f * (rp2 - rp0);
            const float Iy = 3.0f * (rp0 - rm0) + 10.0f * (rp1 - rm1) + 3.0f * (rp2 - rm2);

            const float df = rc1 - sf[(size_t)(g0 + y) * WW + gx];   // ff - sf
            const float w  = wxw * wtab[y];

            sA += w * Ix * Ix;
            sB += w * Ix * Iy;
            sD += w * Iy * Iy;
            sX += w * Ix * df;
            sY += w * Iy * df;

            rm0 = rc0; rm1 = rc1; rm2 = rc2;
            rc0 = rp0; rc1 = rp1; rc2 = rp2;
        }

        colsum[0][lx] = sA;
        colsum[1][lx] = sB;
        colsum[2][lx] = sD;
        colsum[3][lx] = sX;
        colsum[4][lx] = sY;
    }
    __syncthreads();

    // reduce 21 columns -> per-window sums (12 windows x 5 sums = 60 threads)
    if (lx < WPB * 5) {
        const int w = lx / 5;
        const int s = lx % 5;
        float sum = 0.0f;
        #pragma unroll
        for (int j = 0; j < WINN; ++j) sum += colsum[s][w * WINN + j];
        red[w][s] = sum;
    }
    __syncthreads();

    // solve 2x2 per window and store
    if (lx < WPB) {
        const float A  = red[lx][0];
        const float Bv = red[lx][1];
        const float D  = red[lx][2];
        const float Bx = red[lx][3];
        const float By = red[lx][4];

        const float det = A * D - Bv * Bv;
        const float inv = (det != 0.0f) ? (1.0f / det) : 0.0f;
        const float vx  = inv * ( D * Bx - Bv * By);
        const float vy  = inv * (-Bv * Bx + A  * By);

        const int wxg = seg * WPB + lx;         // global window column 0..47
        const float wpx = 2.0f * (float)(wxg * WINN + WINN / 2) / (float)WW - 1.0f;
        const float wpy = 2.0f * (float)(hy  * WINN + WINN / 2) / (float)HH - 1.0f;

        const int t = hy * WSN + wxg;
        float4 o;
        o.x = wpx;
        o.y = wpy;
        o.z = vx / 48.0f + wpx;                 // CENTER_REL = [W/WIN, H/WIN] = [48,48]
        o.w = vy / 48.0f + wpy;
        reinterpret_cast<float4*>(out)[(size_t)b * TN + t] = o;
    }
}

extern "C" void kernel_launch(void* const* d_in, const int* in_sizes, int n_in,
                              void* d_out, int out_size, void* d_ws, size_t ws_size,
                              hipStream_t stream) {
    const float* imgs = (const float*)d_in[0];
    float* out = (float*)d_out;

    const int B = in_sizes[0] / (2 * HH * WW);  // 16
    const dim3 grid(B * HSN * SEGS);            // 3072 blocks
    SparseOptFlowLK_kernel<<<grid, 256, 0, stream>>>(imgs, out);
}